// Round 10
// baseline (1341.339 us; speedup 1.0000x reference)
//
#include <hip/hip_runtime.h>
#include <math.h>

#define NXQ 729
#define M2Q 128
#define MQ  857
#define BQ  16
#define QPEN_ 0.1
#define SIGMA_ 0.1

typedef double d4 __attribute__((ext_vector_type(4)));

// workspace offsets (in doubles)
constexpr int OFF_P    = 0;                        // 16x729
constexpr int OFF_H2   = OFF_P + BQ*NXQ;           // 128
constexpr int OFF_Z    = OFF_H2 + M2Q;             // 16x729
constexpr int OFF_S    = OFF_Z + BQ*NXQ;           // 16x857
constexpr int OFF_LAM  = OFF_S + BQ*MQ;            // 16x857
constexpr int OFF_D    = OFF_LAM + BQ*MQ;          // 16x857
constexpr int OFF_RP   = OFF_D + BQ*MQ;            // 16x857
constexpr int OFF_V    = OFF_RP + BQ*MQ;           // 16x857
constexpr int OFF_AINV = OFF_V + BQ*MQ;            // 16x729
constexpr int OFF_Y    = OFF_AINV + BQ*NXQ;        // 16x729
constexpr int OFF_GZ2  = OFF_Y + BQ*NXQ;           // 16x128
constexpr int OFF_Q2   = OFF_GZ2 + BQ*M2Q;         // 16x128
constexpr int OFF_USOL = OFF_Q2 + BQ*M2Q;          // 16x128
constexpr int OFF_G2B  = OFF_USOL + BQ*M2Q;        // 16x128
constexpr int OFF_TP   = OFF_G2B + BQ*M2Q;         // 12x16x128 t partials
constexpr int OFF_CMIN = OFF_TP + 12*BQ*M2Q;       // 13x16 alpha partial mins
constexpr int OFF_SG   = OFF_CMIN + 13*BQ + 48;    // 16x128x128 S matrices
constexpr int OFF_DZS  = OFF_SG;                   // 16x768 ALIASES SG prefix
                                                   // (S consumed by in-kernel solve before dzupd
                                                   //  writes DZS; next pssolve rewrites SG)
constexpr int OFF_CNTD = OFF_SG + BQ*M2Q*M2Q;      // dz->upd counters (16 uints), 8 dbl
constexpr int OFF_CNT2 = OFF_CNTD + 8;             // ps->solve counters (16 uints), 8 dbl

// solve LDS layout (doubles)
constexpr int L_SL   = 0;                  // 128 x 129 = 16512
constexpr int L_US   = 16512;              // 128
constexpr int L_INVD = 16640;              // 128
constexpr int L_RED  = 16768;              // 8
constexpr int SH_PSS = (16776) * 8;        // 134208 B -> 1 block/CU (ps needs 69632 B)

__device__ __forceinline__ double wred_sum(double v) {
#pragma unroll
  for (int off = 32; off > 0; off >>= 1) v += __shfl_down(v, off, 64);
  return v;
}
__device__ __forceinline__ double wred_min(double v) {
#pragma unroll
  for (int off = 32; off > 0; off >>= 1) v = fmin(v, __shfl_down(v, off, 64));
  return v;
}
// f32-seeded fp64 rsqrt: seed err ~1e-7 -> 2 Newton -> ~1 ulp. Avoids OCML branches.
__device__ __forceinline__ double rsqrt64(double x) {
  double r = (double)rsqrtf((float)x);
  r = r * (1.5 - 0.5 * x * r * r);
  r = r * (1.5 - 0.5 * x * r * r);
  return r;
}

// ---------------------------------------------------------------------------
// init: grid 144 x 512. Blocks 0..15: per-batch state + first-iter elementwise
// prep (mu=1 exactly). Blocks 16..143: h2 row r + m2-row prep for all batches.
// ---------------------------------------------------------------------------
__global__ __launch_bounds__(512)
void init_kernel(const float* __restrict__ puzzles, const float* __restrict__ G2,
                 const float* __restrict__ z2in, const float* __restrict__ s2in,
                 double* __restrict__ ws) {
  const int blk = blockIdx.x;
  const int tid = threadIdx.x, wave = tid >> 6, lane = tid & 63;
  __shared__ double sm[32];
  if (blk < BQ) {
    const int bb = blk;
    for (int i = tid; i < NXQ; i += 512) {
      ws[OFF_P + bb * NXQ + i] = -(double)puzzles[bb * NXQ + i];
      ws[OFF_Z + bb * NXQ + i] = 0.0;
      ws[OFF_AINV + bb * NXQ + i] = 1.0 / (QPEN_ + 1.0);
      ws[OFF_RP + bb * MQ + i] = 1.0;       // s - z = 1
      ws[OFF_V + bb * MQ + i] = SIGMA_;     // 0.1/1 - 1 + 1*1
    }
    for (int i = tid; i < MQ; i += 512) {
      ws[OFF_S + bb * MQ + i] = 1.0;
      ws[OFF_LAM + bb * MQ + i] = 1.0;
      ws[OFF_D + bb * MQ + i] = 1.0;
    }
    if (tid < M2Q) ws[OFF_GZ2 + bb * M2Q + tid] = 0.0;
    if (tid == 0) {
      ((unsigned*)(ws + OFF_CNTD))[bb] = 0u;
      ((unsigned*)(ws + OFF_CNT2))[bb] = 0u;
    }
  } else {
    const int r = blk - 16;
    double acc = 0.0;
    for (int kx = tid; kx < NXQ; kx += 512)
      acc += (double)G2[r * NXQ + kx] * (double)z2in[kx];
    acc = wred_sum(acc);
    if (lane == 0) sm[wave] = acc;
    __syncthreads();
    if (tid == 0) {
      double t = 0.0;
#pragma unroll
      for (int w = 0; w < 8; ++w) t += sm[w];
      const double h2r = t + (double)s2in[r];
      ws[OFF_H2 + r] = h2r;
      sm[16] = h2r;
    }
    __syncthreads();
    if (tid < BQ) {
      const double rp2 = 1.0 - sm[16];               // gz2(0) + s(1) - h2
      ws[OFF_RP + tid * MQ + NXQ + r] = rp2;
      ws[OFF_V  + tid * MQ + NXQ + r] = rp2 - 0.9;   // 0.1 - 1 + rp2
      ws[OFF_Q2 + tid * M2Q + r] = rp2 + 0.1;        // lam + v
    }
  }
}

// ---------------------------------------------------------------------------
// solve body: factor K = S + D2inv, solve K u = t. Runs on one 512-thr block.
// ---------------------------------------------------------------------------
__device__ void solve_body(double* __restrict__ ws, double* __restrict__ sm, const int b) {
  const int tid = threadIdx.x, wave = tid >> 6, lane = tid & 63;
  double (*Sl)[129] = (double(*)[129])(sm + L_SL);
  double* us   = sm + L_US;
  double* invd = sm + L_INVD;
  double* red  = sm + L_RED;
  double* s_   = ws + OFF_S   + b * MQ;
  double* lam_ = ws + OFF_LAM + b * MQ;
  double* Sgb  = ws + OFF_SG  + b * M2Q * M2Q;

  {
    const double2* __restrict__ Sg2 = (const double2*)Sgb;
    for (int idx = tid; idx < M2Q * M2Q / 2; idx += 512) {
      const double2 v = Sg2[idx];
      const int r = idx >> 6, c = (idx & 63) * 2;
      Sl[r][c] = v.x; Sl[r][c + 1] = v.y;
    }
  }
  if (tid < M2Q) {
    double t = 0.0;
#pragma unroll
    for (int c = 0; c < 12; ++c) t += ws[OFF_TP + (c * BQ + b) * M2Q + tid];
    us[tid] = t;
  }
  __syncthreads();
  if (tid < M2Q) Sl[tid][tid] += s_[NXQ + tid] / lam_[NXQ + tid];
  __syncthreads();

  // runtime probe of f64 MFMA C/D register->(row,col) mapping (verified R4)
  int rowm[4], colm[4];
  {
    const int rc = lane & 15, kq = lane >> 4;
    const double avr = (kq == 0) ? (double)rc : 0.0;
    const double bv1 = (kq == 0) ? 1.0 : 0.0;
    const double av1 = (kq == 0) ? 1.0 : 0.0;
    const double bvc = (kq == 0) ? (double)rc : 0.0;
    d4 zero = {0.0, 0.0, 0.0, 0.0};
    d4 dr = __builtin_amdgcn_mfma_f64_16x16x4f64(avr, bv1, zero, 0, 0, 0);
    d4 dc = __builtin_amdgcn_mfma_f64_16x16x4f64(av1, bvc, zero, 0, 0, 0);
#pragma unroll
    for (int e = 0; e < 4; ++e) { rowm[e] = (int)dr[e]; colm[e] = (int)dc[e]; }
  }

  // blocked Cholesky (NB=16) with forward substitution as extra TRSM row
  for (int kb = 0; kb < 8; ++kb) {
    const int K0 = kb * 16, J0 = K0 + 16, T = 128 - J0;
    if (wave == 0 && lane < 16) {
      const int r = lane;
      double a[16];
#pragma unroll
      for (int c = 0; c < 16; ++c) a[c] = Sl[K0 + r][K0 + c];
#pragma unroll
      for (int c = 0; c < 16; ++c) {
        const double dcc = __shfl(a[c], c, 64);
        const double rs = rsqrt64(dcc);
        a[c] *= rs;
        if (lane == c) invd[K0 + c] = rs;
#pragma unroll
        for (int k2 = c + 1; k2 < 16; ++k2) {
          const double lkc = __shfl(a[c], k2, 64);
          a[k2] = fma(-a[c], lkc, a[k2]);
        }
      }
#pragma unroll
      for (int c = 0; c < 16; ++c) Sl[K0 + r][K0 + c] = a[c];
    }
    __syncthreads();

    if (tid <= T) {
      const bool isU = (tid == T);
      double l[16];
      if (isU) {
#pragma unroll
        for (int c = 0; c < 16; ++c) l[c] = us[K0 + c];
      } else {
#pragma unroll
        for (int c = 0; c < 16; ++c) l[c] = Sl[J0 + tid][K0 + c];
      }
#pragma unroll
      for (int c = 0; c < 16; ++c) {
        const double lc = l[c] * invd[K0 + c];
        l[c] = lc;
#pragma unroll
        for (int k2 = c + 1; k2 < 16; ++k2)
          l[k2] = fma(-lc, Sl[K0 + k2][K0 + c], l[k2]);
      }
      if (isU) {
#pragma unroll
        for (int c = 0; c < 16; ++c) us[K0 + c] = l[c];
      } else {
#pragma unroll
        for (int c = 0; c < 16; ++c) Sl[J0 + tid][K0 + c] = l[c];
      }
    }
    __syncthreads();

    if (kb < 7) {
      if (tid < T) {
        double acc = 0.0;
#pragma unroll
        for (int c = 0; c < 16; ++c) acc = fma(Sl[J0 + tid][K0 + c], us[K0 + c], acc);
        us[J0 + tid] -= acc;
      }
      const int Tb = 7 - kb;
      const int rc = lane & 15, kq = lane >> 4;
      for (int idx = wave; idx < Tb * Tb; idx += 8) {
        const int i0 = J0 + (idx / Tb) * 16;
        const int j0 = J0 + (idx % Tb) * 16;
        d4 acc;
#pragma unroll
        for (int e = 0; e < 4; ++e) acc[e] = Sl[i0 + rowm[e]][j0 + colm[e]];
#pragma unroll
        for (int m = 0; m < 4; ++m) {
          const double av = -Sl[i0 + rc][K0 + 4 * m + kq];
          const double bv =  Sl[j0 + rc][K0 + 4 * m + kq];
          acc = __builtin_amdgcn_mfma_f64_16x16x4f64(av, bv, acc, 0, 0, 0);
        }
#pragma unroll
        for (int e = 0; e < 4; ++e) Sl[i0 + rowm[e]][j0 + colm[e]] = acc[e];
      }
    }
    __syncthreads();
  }

  // backward substitution L^T u = u'
  for (int kb = 7; kb >= 0; --kb) {
    const int K0 = kb * 16;
    if (kb < 7) {
      // one column per 32-lane half-wave: 16 cols x 32 lanes = 512 threads
      const int col = tid >> 5, hl = tid & 31;
      double part = 0.0;
      for (int k = K0 + 16 + hl; k < 128; k += 32) part = fma(Sl[k][K0 + col], us[k], part);
#pragma unroll
      for (int off = 16; off > 0; off >>= 1) part += __shfl_down(part, off, 64);
      if (hl == 0) us[K0 + col] -= part;
      __syncthreads();
    }
    if (wave == 0 && lane < 16) {
      const int j = lane;
      double colv[16];
#pragma unroll
      for (int c = 0; c < 16; ++c) colv[c] = Sl[K0 + c][K0 + j];
      double x = us[K0 + j];
      const double iv = invd[K0 + j];
#pragma unroll
      for (int cc = 0; cc < 16; ++cc) {
        const int c = 15 - cc;
        const double xiv = x * iv;
        const double uc = __shfl(xiv, c, 64);
        if (j == c) x = xiv;
        else if (j < c) x = fma(-colv[c], uc, x);
      }
      us[K0 + j] = x;
    }
    __syncthreads();
  }

  // tail: write u, g2b = D2inv*u; m2-part ratio min -> cmin slot 12
  double lmin = 1e300;
  if (tid < M2Q) {
    const double u = us[tid];
    ws[OFF_USOL + b * M2Q + tid] = u;
    const double g = (s_[NXQ + tid] / lam_[NXQ + tid]) * u;
    ws[OFF_G2B + b * M2Q + tid] = g;
    const int i = NXQ + tid;
    const double dsi = -ws[OFF_RP + b * MQ + i] - g;
    const double dlami = ws[OFF_V + b * MQ + i] + ws[OFF_D + b * MQ + i] * g;
    if (dsi < 0.0)   lmin = fmin(lmin, -s_[i] / dsi);
    if (dlami < 0.0) lmin = fmin(lmin, -lam_[i] / dlami);
  }
  if (tid < 128) {
    lmin = wred_min(lmin);
    if (lane == 0) red[wave] = lmin;
  }
  __syncthreads();
  if (tid == 0) ws[OFF_CMIN + 12 * BQ + b] = fmin(red[0], red[1]);
}

// ---------------------------------------------------------------------------
// pssolve: grid (16 tiles, 16 batches) x 512.
// tile<12: prep chunk (rhs,y + t partials). All: sbuild 32x32 tile.
// Last-arriving block per batch continues into solve_body (no polling).
// ---------------------------------------------------------------------------
__global__ __launch_bounds__(512)
void pssolve_kernel(const float* __restrict__ G2, double* __restrict__ ws) {
  const int tile = blockIdx.x, b = blockIdx.y;
  const int tid = threadIdx.x, wave = tid >> 6, lane = tid & 63;
  extern __shared__ double sm[];
  __shared__ int sflag;

  // ---- prep chunk (R9 verbatim) ----
  if (tile < 12) {
    double* uvec = sm;           // 128
    double* part = sm + 128;     // 512
    double* yl   = sm + 640;     // 64
    const int c0 = tile * 64;
    if (tid < M2Q) uvec[tid] = ws[OFF_Q2 + b * M2Q + tid];
    __syncthreads();
    const int kk = tid & 63, rq = tid >> 6;
    const int k = c0 + kk;
    const int kg = (k < NXQ) ? k : (NXQ - 1);
    {
      const float* gp = G2 + (rq * 16) * NXQ + kg;
      double acc = 0.0;
#pragma unroll
      for (int j = 0; j < 16; ++j) acc = fma((double)gp[j * NXQ], uvec[rq * 16 + j], acc);
      part[rq * 64 + kk] = acc;
    }
    __syncthreads();
    if (tid < 64) {
      const int k2 = c0 + tid;
      double y = 0.0;
      if (k2 < NXQ) {
        double w = 0.0;
#pragma unroll
        for (int q = 0; q < 8; ++q) w += part[q * 64 + tid];
        const double rhsk = -(QPEN_ * ws[OFF_Z + b * NXQ + k2] + ws[OFF_P + b * NXQ + k2]
                              - ws[OFF_LAM + b * MQ + k2] - ws[OFF_V + b * MQ + k2] + w);
        y = ws[OFF_AINV + b * NXQ + k2] * rhsk;
        ws[OFF_Y + b * NXQ + k2] = y;
      }
      yl[tid] = y;
    }
    __syncthreads();
    const double yv = yl[lane];
#pragma unroll
    for (int jr = 0; jr < 16; ++jr) {
      const int r = (tid >> 6) * 16 + jr;
      double v = (double)G2[r * NXQ + kg] * yv;
      v = wred_sum(v);
      if (lane == 0) ws[OFF_TP + (tile * BQ + b) * M2Q + r] = v;
    }
    __syncthreads();
  }

  // ---- sbuild (R9 wave-gated core at 512 thr) ----
  {
    const int R0 = (tile >> 2) * 32, C0 = (tile & 3) * 32;
    double* As = sm + wave * 2176;
    double* Bs = As + 1088;
    const double* __restrict__ ainv = ws + OFF_AINV + b * NXQ;
    const int k0w = wave * 183;
    const int kend = min(k0w + 183, NXQ);
    const int rg4 = (lane >> 3) * 4, cg4 = (lane & 7) * 4;
    double acc[4][4];
#pragma unroll
    for (int i = 0; i < 4; ++i)
#pragma unroll
      for (int j = 0; j < 4; ++j) acc[i][j] = 0.0;

    const int kk2 = lane & 31;
    for (int ch = 0; ch < 6; ++ch) {
      __syncthreads();
      if (wave < 4) {
        const int k = k0w + ch * 32 + kk2;
        const bool ok = (k < kend);
        const double aik = ok ? ainv[k] : 0.0;
#pragma unroll
        for (int it = 0; it < 16; ++it) {
          const int rr = (it << 1) | (lane >> 5);
          double av = 0.0, bv = 0.0;
          if (ok) {
            av = (double)G2[(R0 + rr) * NXQ + k] * aik;
            bv = (double)G2[(C0 + rr) * NXQ + k];
          }
          As[kk2 * 34 + rr] = av;
          Bs[kk2 * 34 + rr] = bv;
        }
      }
      __syncthreads();
      if (wave < 4) {
#pragma unroll 8
        for (int q = 0; q < 32; ++q) {
          const double a0 = As[q*34 + rg4 + 0], a1 = As[q*34 + rg4 + 1],
                       a2 = As[q*34 + rg4 + 2], a3 = As[q*34 + rg4 + 3];
          const double b0 = Bs[q*34 + cg4 + 0], b1 = Bs[q*34 + cg4 + 1],
                       b2 = Bs[q*34 + cg4 + 2], b3 = Bs[q*34 + cg4 + 3];
          acc[0][0] += a0*b0; acc[0][1] += a0*b1; acc[0][2] += a0*b2; acc[0][3] += a0*b3;
          acc[1][0] += a1*b0; acc[1][1] += a1*b1; acc[1][2] += a1*b2; acc[1][3] += a1*b3;
          acc[2][0] += a2*b0; acc[2][1] += a2*b1; acc[2][2] += a2*b2; acc[2][3] += a2*b3;
          acc[3][0] += a3*b0; acc[3][1] += a3*b1; acc[3][2] += a3*b2; acc[3][3] += a3*b3;
        }
      }
    }
    __syncthreads();
    if (wave < 4) {
#pragma unroll
      for (int i = 0; i < 4; ++i)
#pragma unroll
        for (int j = 0; j < 4; ++j)
          As[(rg4 + i) * 32 + cg4 + j] = acc[i][j];
    }
    __syncthreads();
    double* __restrict__ Sgb = ws + OFF_SG + b * (M2Q * M2Q);
    for (int idx = tid; idx < 1024; idx += 512) {
      const double v = sm[idx] + sm[2176 + idx] + sm[4352 + idx] + sm[6528 + idx];
      Sgb[(R0 + (idx >> 5)) * M2Q + C0 + (idx & 31)] = v;
    }
  }
  __syncthreads();

  // ---- handshake: 16th-arriving block of batch b runs the solve ----
  if (tid == 0) {
    unsigned* cnt2 = (unsigned*)(ws + OFF_CNT2);
    __threadfence();   // release this block's SG tile + TP writes
    const unsigned prev = __hip_atomic_fetch_add(&cnt2[b], 1u, __ATOMIC_ACQ_REL, __HIP_MEMORY_SCOPE_AGENT);
    sflag = (prev == 15u) ? 1 : 0;
    if (sflag) {
      __threadfence();   // acquire peers' SG tiles + TP
      __hip_atomic_store(&cnt2[b], 0u, __ATOMIC_RELAXED, __HIP_MEMORY_SCOPE_AGENT);
    }
  }
  __syncthreads();
  if (!sflag) return;
  solve_body(ws, sm, b);
}

// ---------------------------------------------------------------------------
// dzupd: grid (12 chunks, 16 batches) x 512. R9 verbatim.
// ---------------------------------------------------------------------------
__global__ __launch_bounds__(512)
void dzupd_kernel(const float* __restrict__ G2, double* __restrict__ ws,
                  float* __restrict__ out, const int last) {
  const int chunk = blockIdx.x, b = blockIdx.y;
  const int tid = threadIdx.x, lane = tid & 63, wave = tid >> 6;
  __shared__ double uvec[128];
  __shared__ double part[512];
  __shared__ double red[8];
  __shared__ double sc2[2];
  __shared__ int updflag;
  unsigned* cnt = (unsigned*)(ws + OFF_CNTD);
  const int c0 = chunk * 64;
  if (tid < M2Q) uvec[tid] = ws[OFF_USOL + b * M2Q + tid];
  __syncthreads();
  const int kk = tid & 63, rq = tid >> 6;
  const int k = c0 + kk;
  const int kg = (k < NXQ) ? k : (NXQ - 1);
  {
    const float* gp = G2 + (rq * 16) * NXQ + kg;
    double acc = 0.0;
#pragma unroll
    for (int j = 0; j < 16; ++j) acc = fma((double)gp[j * NXQ], uvec[rq * 16 + j], acc);
    part[rq * 64 + kk] = acc;
  }
  __syncthreads();
  double lmin = 1e300;
  if (tid < 64) {
    const int k2 = c0 + tid;
    if (k2 < NXQ) {
      double w = 0.0;
#pragma unroll
      for (int q = 0; q < 8; ++q) w += part[q * 64 + tid];
      const double dz = ws[OFF_Y + b * NXQ + k2] - ws[OFF_AINV + b * NXQ + k2] * w;
      ws[OFF_DZS + b * 768 + k2] = dz;
      const double dsi = dz - ws[OFF_RP + b * MQ + k2];
      const double dlami = ws[OFF_V + b * MQ + k2] - ws[OFF_D + b * MQ + k2] * dz;
      if (dsi < 0.0)   lmin = fmin(lmin, -ws[OFF_S + b * MQ + k2] / dsi);
      if (dlami < 0.0) lmin = fmin(lmin, -ws[OFF_LAM + b * MQ + k2] / dlami);
    }
    lmin = wred_min(lmin);
    if (tid == 0) ws[OFF_CMIN + chunk * BQ + b] = lmin;
  }
  __syncthreads();
  if (tid == 0) {
    __threadfence();
    const unsigned prev = __hip_atomic_fetch_add(&cnt[b], 1u, __ATOMIC_ACQ_REL, __HIP_MEMORY_SCOPE_AGENT);
    updflag = (prev == 11u) ? 1 : 0;
    if (updflag) __threadfence();
  }
  __syncthreads();
  if (!updflag) return;

  double* z    = ws + OFF_Z   + b * NXQ;
  double* s_   = ws + OFF_S   + b * MQ;
  double* lam_ = ws + OFF_LAM + b * MQ;
  double* dd   = ws + OFF_D   + b * MQ;
  double* rp   = ws + OFF_RP  + b * MQ;
  double* vv   = ws + OFF_V   + b * MQ;
  double* gz2  = ws + OFF_GZ2 + b * M2Q;
  if (tid == 0) {
    double m = 1e300;
#pragma unroll
    for (int c = 0; c < 13; ++c) m = fmin(m, ws[OFF_CMIN + c * BQ + b]);
    sc2[0] = fmin(1.0, 0.99 * m);
    __hip_atomic_store(&cnt[b], 0u, __ATOMIC_RELAXED, __HIP_MEMORY_SCOPE_AGENT);
  }
  __syncthreads();
  const double alpha = sc2[0];
  for (int i = tid; i < NXQ; i += 512) {
    const double dz = ws[OFF_DZS + b * 768 + i];
    s_[i]   += alpha * (dz - rp[i]);
    lam_[i] += alpha * (vv[i] - dd[i] * dz);
    const double zi = z[i] + alpha * dz;
    z[i] = zi;
    out[b * NXQ + i] = (float)zi;
  }
  if (tid < M2Q) {
    const int i = NXQ + tid;
    const double g = ws[OFF_G2B + b * M2Q + tid];
    s_[i]   += alpha * (-rp[i] - g);
    lam_[i] += alpha * (vv[i] + dd[i] * g);
    gz2[tid] += alpha * g;
  }
  __syncthreads();
  if (last) return;

  double musum = 0.0;
  for (int i = tid; i < MQ; i += 512) {
    const double si = s_[i], li = lam_[i];
    dd[i] = li / si;
    const double rpi = (i < NXQ) ? (si - z[i]) : (gz2[i - NXQ] + si - ws[OFF_H2 + i - NXQ]);
    rp[i] = rpi;
    musum += si * li;
  }
  musum = wred_sum(musum);
  if (lane == 0) red[wave] = musum;
  __syncthreads();
  if (tid == 0) {
    double t = 0.0;
#pragma unroll
    for (int w = 0; w < 8; ++w) t += red[w];
    sc2[1] = SIGMA_ * (t / (double)MQ);
  }
  __syncthreads();
  const double smu = sc2[1];
  for (int i = tid; i < MQ; i += 512) {
    const double si = s_[i], li = lam_[i];
    const double vi = smu / si - li + dd[i] * rp[i];
    vv[i] = vi;
    if (i >= NXQ) ws[OFF_Q2 + b * M2Q + (i - NXQ)] = li + vi;
    else ws[OFF_AINV + b * NXQ + i] = 1.0 / (QPEN_ + dd[i]);
  }
}

extern "C" void kernel_launch(void* const* d_in, const int* in_sizes, int n_in,
                              void* d_out, int out_size, void* d_ws, size_t ws_size,
                              hipStream_t stream) {
  const float* puzzles = (const float*)d_in[0];
  const float* G2      = (const float*)d_in[1];
  const float* z2      = (const float*)d_in[2];
  const float* s2      = (const float*)d_in[3];
  float* out = (float*)d_out;
  double* ws = (double*)d_ws;

  (void)hipFuncSetAttribute(reinterpret_cast<const void*>(&pssolve_kernel),
                            hipFuncAttributeMaxDynamicSharedMemorySize, SH_PSS);

  init_kernel<<<dim3(16 + M2Q), dim3(512), 0, stream>>>(puzzles, G2, z2, s2, ws);
  pssolve_kernel<<<dim3(16, BQ), dim3(512), SH_PSS, stream>>>(G2, ws);
  for (int it = 0; it < 10; ++it) {
    dzupd_kernel<<<dim3(12, BQ), dim3(512), 0, stream>>>(G2, ws, out, (it == 9) ? 1 : 0);
    if (it < 9)
      pssolve_kernel<<<dim3(16, BQ), dim3(512), SH_PSS, stream>>>(G2, ws);
  }
}